// Round 1
// baseline (525.694 us; speedup 1.0000x reference)
//
#include <hip/hip_runtime.h>

typedef __bf16 bf16x8 __attribute__((ext_vector_type(8)));
typedef __bf16 bf16x4 __attribute__((ext_vector_type(4)));
typedef float  f32x4  __attribute__((ext_vector_type(4)));

#define MFMA16(a, b, c) __builtin_amdgcn_mfma_f32_16x16x32_bf16((a), (b), (c), 0, 0, 0)

__device__ __forceinline__ float sigm(float x) { return 1.0f / (1.0f + __expf(-x)); }

// ---- packed bf16 weight layout (element offsets inside d_ws) ----
enum : int {
  ENC_W0_OFF  = 0,        // 16 x 128 x 256
  ENC_W1_OFF  = 524288,   // 16 x 64 x 128
  ENC_W2_OFF  = 655360,   // 16 x 32 x 64
  DEC_W0_OFF  = 688128,   // 16 x 64 x 32
  DEC_W1_OFF  = 720896,   // 16 x 128 x 64
  DEC_W2_OFF  = 851968,   // 16 x 256 x 128
  COMP_W0_OFF = 1376256,  // 256 x 512  (folded [z,z])
  COMP_W1_OFF = 1507328,  // 128 x 768
  COMP_W2_OFF = 1605632,  // 64 x 640
  COMP_W3_OFF = 1646592,  // 32 x 576
  COMP_W4_OFF = 1665024,  // 16 x 544
  COMP_W5_OFF = 1673728,  // 32 x 544  (528 padded to 544, pad = 0)
  DCMP_W0_OFF = 1691136,  // 256 x 32  (folded)
  DCMP_W1_OFF = 1699328,  // 128 x 288
  DCMP_W2_OFF = 1736192,  // 64 x 160
  DCMP_W3_OFF = 1746432,  // 32 x 96
  DCMP_W4_OFF = 1749504,  // 16 x 64
  DCMP_W5_OFF = 1750528,  // 512 x 64  (48 padded to 64, pad = 0)
  W_TOTAL     = 1783296,
};

#define ZS_BYTES_OFF (4u * 1024u * 1024u)            // z_stack / z_stack_hat: 32768*512*2 = 32 MB
#define Z_BYTES_OFF  (ZS_BYTES_OFF + 33554432u)      // z: 32768*32*2 = 2 MB

// =============================== weight prep ===============================
__global__ void prep_kernel(
    const float* __restrict__ ew0, const float* __restrict__ ew1, const float* __restrict__ ew2,
    const float* __restrict__ dw0, const float* __restrict__ dw1, const float* __restrict__ dw2,
    const float* __restrict__ cw0, const float* __restrict__ cw1, const float* __restrict__ cw2,
    const float* __restrict__ cw3, const float* __restrict__ cw4, const float* __restrict__ cw5,
    const float* __restrict__ xw0, const float* __restrict__ xw1, const float* __restrict__ xw2,
    const float* __restrict__ xw3, const float* __restrict__ xw4, const float* __restrict__ xw5,
    __bf16* __restrict__ wb)
{
  for (int i = blockIdx.x * blockDim.x + threadIdx.x; i < W_TOTAL; i += gridDim.x * blockDim.x) {
    float v;
    if      (i < ENC_W1_OFF)  v = ew0[i - ENC_W0_OFF];
    else if (i < ENC_W2_OFF)  v = ew1[i - ENC_W1_OFF];
    else if (i < DEC_W0_OFF)  v = ew2[i - ENC_W2_OFF];
    else if (i < DEC_W1_OFF)  v = dw0[i - DEC_W0_OFF];
    else if (i < DEC_W2_OFF)  v = dw1[i - DEC_W1_OFF];
    else if (i < COMP_W0_OFF) v = dw2[i - DEC_W2_OFF];
    else if (i < COMP_W1_OFF) { int t = i - COMP_W0_OFF; int o = t >> 9, c = t & 511;
                                v = cw0[o * 1024 + c] + cw0[o * 1024 + 512 + c]; }
    else if (i < COMP_W2_OFF) v = cw1[i - COMP_W1_OFF];
    else if (i < COMP_W3_OFF) v = cw2[i - COMP_W2_OFF];
    else if (i < COMP_W4_OFF) v = cw3[i - COMP_W3_OFF];
    else if (i < COMP_W5_OFF) v = cw4[i - COMP_W4_OFF];
    else if (i < DCMP_W0_OFF) { int t = i - COMP_W5_OFF; int o = t / 544, c = t % 544;
                                v = (c < 528) ? cw5[o * 528 + c] : 0.0f; }
    else if (i < DCMP_W1_OFF) { int t = i - DCMP_W0_OFF; int o = t >> 5, c = t & 31;
                                v = xw0[o * 64 + c] + xw0[o * 64 + 32 + c]; }
    else if (i < DCMP_W2_OFF) v = xw1[i - DCMP_W1_OFF];
    else if (i < DCMP_W3_OFF) v = xw2[i - DCMP_W2_OFF];
    else if (i < DCMP_W4_OFF) v = xw3[i - DCMP_W3_OFF];
    else if (i < DCMP_W5_OFF) v = xw4[i - DCMP_W4_OFF];
    else                      { int t = i - DCMP_W5_OFF; int o = t >> 6, c = t & 63;
                                v = (c < 48) ? xw5[o * 48 + c] : 0.0f; }
    wb[i] = (__bf16)v;
  }
}

// =============================== encoder ===================================
// 16 independent MLPs 256 -> 128 -> 64 -> 32 (sigmoid after L0, L1).
// Block = (batch tile of 64) x (one encoder). 256 threads = 4 waves.
__global__ __launch_bounds__(256, 2)
void enc_kernel(const float* __restrict__ x, const __bf16* __restrict__ wb,
                const float* __restrict__ b0, const float* __restrict__ b1,
                const float* __restrict__ b2, __bf16* __restrict__ zout)
{
  __shared__ __bf16 xs[64][264];
  __shared__ __bf16 h1[64][136];
  __shared__ __bf16 h2[64][72];
  const int e = blockIdx.y;
  const int m0 = blockIdx.x * 64;
  const int tid = threadIdx.x;
  const int lane = tid & 63, wv = tid >> 6;
  const int l15 = lane & 15, hi8 = (lane >> 4) * 8, rloc = (lane >> 4) * 4;

  const float* xblk = x + (size_t)m0 * 4096 + e * 256;
  #pragma unroll
  for (int i = 0; i < 16; ++i) {
    int idx = tid + i * 256;
    int r = idx >> 6, c4 = (idx & 63) * 4;
    float4 v = *(const float4*)(xblk + (size_t)r * 4096 + c4);
    bf16x4 o = { (__bf16)v.x, (__bf16)v.y, (__bf16)v.z, (__bf16)v.w };
    *(bf16x4*)&xs[r][c4] = o;
  }
  __syncthreads();

  // L0: N=128, K=256. wave covers cols [wv*32, wv*32+32)
  {
    const __bf16* W = wb + ENC_W0_OFF + e * 32768;
    f32x4 acc[4][2];
    #pragma unroll
    for (int cf = 0; cf < 2; ++cf) {
      float bv = b0[e * 128 + wv * 32 + cf * 16 + l15];
      f32x4 bvv = {bv, bv, bv, bv};
      #pragma unroll
      for (int rf = 0; rf < 4; ++rf) acc[rf][cf] = bvv;
    }
    #pragma unroll
    for (int ks = 0; ks < 8; ++ks) {
      bf16x8 a[4], bb[2];
      #pragma unroll
      for (int rf = 0; rf < 4; ++rf) a[rf] = *(const bf16x8*)&xs[rf * 16 + l15][ks * 32 + hi8];
      #pragma unroll
      for (int cf = 0; cf < 2; ++cf)
        bb[cf] = *(const bf16x8*)(W + (size_t)(wv * 32 + cf * 16 + l15) * 256 + ks * 32 + hi8);
      #pragma unroll
      for (int rf = 0; rf < 4; ++rf)
        #pragma unroll
        for (int cf = 0; cf < 2; ++cf)
          acc[rf][cf] = MFMA16(a[rf], bb[cf], acc[rf][cf]);
    }
    #pragma unroll
    for (int rf = 0; rf < 4; ++rf)
      #pragma unroll
      for (int cf = 0; cf < 2; ++cf)
        #pragma unroll
        for (int r = 0; r < 4; ++r)
          h1[rf * 16 + rloc + r][wv * 32 + cf * 16 + l15] = (__bf16)sigm(acc[rf][cf][r]);
  }
  __syncthreads();

  // L1: N=64, K=128. wave covers cols [wv*16, wv*16+16)
  {
    const __bf16* W = wb + ENC_W1_OFF + e * 8192;
    f32x4 acc[4];
    float bv = b1[e * 64 + wv * 16 + l15];
    f32x4 bvv = {bv, bv, bv, bv};
    #pragma unroll
    for (int rf = 0; rf < 4; ++rf) acc[rf] = bvv;
    #pragma unroll
    for (int ks = 0; ks < 4; ++ks) {
      bf16x8 a[4];
      #pragma unroll
      for (int rf = 0; rf < 4; ++rf) a[rf] = *(const bf16x8*)&h1[rf * 16 + l15][ks * 32 + hi8];
      bf16x8 bb = *(const bf16x8*)(W + (size_t)(wv * 16 + l15) * 128 + ks * 32 + hi8);
      #pragma unroll
      for (int rf = 0; rf < 4; ++rf) acc[rf] = MFMA16(a[rf], bb, acc[rf]);
    }
    #pragma unroll
    for (int rf = 0; rf < 4; ++rf)
      #pragma unroll
      for (int r = 0; r < 4; ++r)
        h2[rf * 16 + rloc + r][wv * 16 + l15] = (__bf16)sigm(acc[rf][r]);
  }
  __syncthreads();

  // L2: N=32, K=64, no sigmoid. waves 0,1 only.
  if (wv < 2) {
    const __bf16* W = wb + ENC_W2_OFF + e * 2048;
    f32x4 acc[4];
    float bv = b2[e * 32 + wv * 16 + l15];
    f32x4 bvv = {bv, bv, bv, bv};
    #pragma unroll
    for (int rf = 0; rf < 4; ++rf) acc[rf] = bvv;
    #pragma unroll
    for (int ks = 0; ks < 2; ++ks) {
      bf16x8 a[4];
      #pragma unroll
      for (int rf = 0; rf < 4; ++rf) a[rf] = *(const bf16x8*)&h2[rf * 16 + l15][ks * 32 + hi8];
      bf16x8 bb = *(const bf16x8*)(W + (size_t)(wv * 16 + l15) * 64 + ks * 32 + hi8);
      #pragma unroll
      for (int rf = 0; rf < 4; ++rf) acc[rf] = MFMA16(a[rf], bb, acc[rf]);
    }
    #pragma unroll
    for (int rf = 0; rf < 4; ++rf)
      #pragma unroll
      for (int r = 0; r < 4; ++r)
        zout[(size_t)(m0 + rf * 16 + rloc + r) * 512 + e * 32 + wv * 16 + l15] = (__bf16)acc[rf][r];
  }
}

// =============================== compressor ================================
// Residual chain on z (512). Each layer: sigma(A_i z + B_i s_{i-1} + b_i).
// Block = 64 batch rows, 4 waves. z staged in LDS; s buffers ping-pong in LDS.
__global__ __launch_bounds__(256, 1)
void comp_kernel(const __bf16* __restrict__ zin, const __bf16* __restrict__ wb,
                 const float* __restrict__ cb0, const float* __restrict__ cb1,
                 const float* __restrict__ cb2, const float* __restrict__ cb3,
                 const float* __restrict__ cb4, const float* __restrict__ cb5,
                 __bf16* __restrict__ zout)
{
  __shared__ __bf16 zs[64][520];
  __shared__ __bf16 sA[64 * 264];   // s0, s2, s4 (stride 264)
  __shared__ __bf16 sB[64 * 136];   // s1, s3     (stride 136)
  const int m0 = blockIdx.x * 64;
  const int tid = threadIdx.x;
  const int lane = tid & 63, wv = tid >> 6;
  const int l15 = lane & 15, hi8 = (lane >> 4) * 8, rloc = (lane >> 4) * 4;

  #pragma unroll
  for (int i = 0; i < 16; ++i) {
    int idx = tid + i * 256;
    int r = idx >> 6, c = (idx & 63) * 8;
    *(bf16x8*)&zs[r][c] = *(const bf16x8*)(zin + (size_t)(m0 + r) * 512 + c);
  }
  __syncthreads();

  const float* biases[6] = {cb0, cb1, cb2, cb3, cb4, cb5};
  const int NFv[6]   = {16, 8, 4, 2, 1, 2};
  const int KS2v[6]  = {0, 8, 4, 2, 1, 1};
  const int WOFFv[6] = {COMP_W0_OFF, COMP_W1_OFF, COMP_W2_OFF, COMP_W3_OFF, COMP_W4_OFF, COMP_W5_OFF};
  const int KTv[6]   = {512, 768, 640, 576, 544, 544};

  #pragma unroll
  for (int L = 0; L < 6; ++L) {
    const int nf = NFv[L];
    const __bf16* W = wb + WOFFv[L];
    const int KT = KTv[L];
    f32x4 acc[4][4];
    #pragma unroll
    for (int j = 0; j < 4; ++j) {
      int c = wv + 4 * j;
      if (c < nf) {
        float bv = biases[L][c * 16 + l15];
        f32x4 bvv = {bv, bv, bv, bv};
        #pragma unroll
        for (int rf = 0; rf < 4; ++rf) acc[rf][j] = bvv;
      }
    }
    // z part: K = 512
    for (int ks = 0; ks < 16; ++ks) {
      bf16x8 a[4];
      #pragma unroll
      for (int rf = 0; rf < 4; ++rf) a[rf] = *(const bf16x8*)&zs[rf * 16 + l15][ks * 32 + hi8];
      #pragma unroll
      for (int j = 0; j < 4; ++j) {
        int c = wv + 4 * j;
        if (c < nf) {
          bf16x8 bb = *(const bf16x8*)(W + (size_t)(c * 16 + l15) * KT + ks * 32 + hi8);
          #pragma unroll
          for (int rf = 0; rf < 4; ++rf) acc[rf][j] = MFMA16(a[rf], bb, acc[rf][j]);
        }
      }
    }
    // s part
    if (L > 0) {
      __bf16* sp = (L & 1) ? sA : sB;
      const int pld = (L & 1) ? 264 : 136;
      for (int ks = 0; ks < KS2v[L]; ++ks) {
        bf16x8 a[4];
        #pragma unroll
        for (int rf = 0; rf < 4; ++rf)
          a[rf] = *(const bf16x8*)&sp[(rf * 16 + l15) * pld + ks * 32 + hi8];
        #pragma unroll
        for (int j = 0; j < 4; ++j) {
          int c = wv + 4 * j;
          if (c < nf) {
            bf16x8 bb = *(const bf16x8*)(W + (size_t)(c * 16 + l15) * KT + 512 + ks * 32 + hi8);
            #pragma unroll
            for (int rf = 0; rf < 4; ++rf) acc[rf][j] = MFMA16(a[rf], bb, acc[rf][j]);
          }
        }
      }
    }
    if (L < 5) {
      __bf16* so = (L & 1) ? sB : sA;
      const int old_ = (L & 1) ? 136 : 264;
      #pragma unroll
      for (int j = 0; j < 4; ++j) {
        int c = wv + 4 * j;
        if (c < nf) {
          #pragma unroll
          for (int rf = 0; rf < 4; ++rf)
            #pragma unroll
            for (int r = 0; r < 4; ++r)
              so[(rf * 16 + rloc + r) * old_ + c * 16 + l15] = (__bf16)sigm(acc[rf][j][r]);
        }
      }
      if (L == 4) {  // zero-pad s4 cols 16..31 (multiplied by zero weight cols, keep non-NaN)
        for (int i = tid; i < 64 * 16; i += 256) sA[(i >> 4) * 264 + 16 + (i & 15)] = (__bf16)0.0f;
      }
      __syncthreads();
    } else {
      #pragma unroll
      for (int j = 0; j < 4; ++j) {
        int c = wv + 4 * j;
        if (c < nf) {
          #pragma unroll
          for (int rf = 0; rf < 4; ++rf)
            #pragma unroll
            for (int r = 0; r < 4; ++r)
              zout[(size_t)(m0 + rf * 16 + rloc + r) * 32 + c * 16 + l15] = (__bf16)acc[rf][j][r];
        }
      }
    }
  }
}

// =============================== decompressor ==============================
__global__ __launch_bounds__(256, 2)
void decomp_kernel(const __bf16* __restrict__ zin, const __bf16* __restrict__ wb,
                   const float* __restrict__ db0, const float* __restrict__ db1,
                   const float* __restrict__ db2, const float* __restrict__ db3,
                   const float* __restrict__ db4, const float* __restrict__ db5,
                   __bf16* __restrict__ zhout)
{
  __shared__ __bf16 zs[64][40];
  __shared__ __bf16 sA[64 * 264];
  __shared__ __bf16 sB[64 * 136];
  const int m0 = blockIdx.x * 64;
  const int tid = threadIdx.x;
  const int lane = tid & 63, wv = tid >> 6;
  const int l15 = lane & 15, hi8 = (lane >> 4) * 8, rloc = (lane >> 4) * 4;

  {
    int r = tid >> 2, c = (tid & 3) * 8;
    *(bf16x8*)&zs[r][c] = *(const bf16x8*)(zin + (size_t)(m0 + r) * 32 + c);
  }
  __syncthreads();

  const float* biases[5] = {db0, db1, db2, db3, db4};
  const int NFv[5]   = {16, 8, 4, 2, 1};
  const int KS2v[5]  = {0, 8, 4, 2, 1};
  const int WOFFv[5] = {DCMP_W0_OFF, DCMP_W1_OFF, DCMP_W2_OFF, DCMP_W3_OFF, DCMP_W4_OFF};
  const int KTv[5]   = {32, 288, 160, 96, 64};

  #pragma unroll
  for (int L = 0; L < 5; ++L) {
    const int nf = NFv[L];
    const __bf16* W = wb + WOFFv[L];
    const int KT = KTv[L];
    f32x4 acc[4][4];
    #pragma unroll
    for (int j = 0; j < 4; ++j) {
      int c = wv + 4 * j;
      if (c < nf) {
        float bv = biases[L][c * 16 + l15];
        f32x4 bvv = {bv, bv, bv, bv};
        #pragma unroll
        for (int rf = 0; rf < 4; ++rf) acc[rf][j] = bvv;
      }
    }
    // z part: K = 32, one k-step
    {
      bf16x8 a[4];
      #pragma unroll
      for (int rf = 0; rf < 4; ++rf) a[rf] = *(const bf16x8*)&zs[rf * 16 + l15][hi8];
      #pragma unroll
      for (int j = 0; j < 4; ++j) {
        int c = wv + 4 * j;
        if (c < nf) {
          bf16x8 bb = *(const bf16x8*)(W + (size_t)(c * 16 + l15) * KT + hi8);
          #pragma unroll
          for (int rf = 0; rf < 4; ++rf) acc[rf][j] = MFMA16(a[rf], bb, acc[rf][j]);
        }
      }
    }
    if (L > 0) {
      __bf16* sp = (L & 1) ? sA : sB;
      const int pld = (L & 1) ? 264 : 136;
      for (int ks = 0; ks < KS2v[L]; ++ks) {
        bf16x8 a[4];
        #pragma unroll
        for (int rf = 0; rf < 4; ++rf)
          a[rf] = *(const bf16x8*)&sp[(rf * 16 + l15) * pld + ks * 32 + hi8];
        #pragma unroll
        for (int j = 0; j < 4; ++j) {
          int c = wv + 4 * j;
          if (c < nf) {
            bf16x8 bb = *(const bf16x8*)(W + (size_t)(c * 16 + l15) * KT + 32 + ks * 32 + hi8);
            #pragma unroll
            for (int rf = 0; rf < 4; ++rf) acc[rf][j] = MFMA16(a[rf], bb, acc[rf][j]);
          }
        }
      }
    }
    {
      __bf16* so = (L & 1) ? sB : sA;
      const int old_ = (L & 1) ? 136 : 264;
      #pragma unroll
      for (int j = 0; j < 4; ++j) {
        int c = wv + 4 * j;
        if (c < nf) {
          #pragma unroll
          for (int rf = 0; rf < 4; ++rf)
            #pragma unroll
            for (int r = 0; r < 4; ++r)
              so[(rf * 16 + rloc + r) * old_ + c * 16 + l15] = (__bf16)sigm(acc[rf][j][r]);
        }
      }
      if (L == 4) {
        for (int i = tid; i < 64 * 16; i += 256) sA[(i >> 4) * 264 + 16 + (i & 15)] = (__bf16)0.0f;
      }
      __syncthreads();
    }
  }

  // final layer: N=512, KT=64 (z cols 0..31, s4 cols 32..47, zeros 48..63)
  {
    const __bf16* W = wb + DCMP_W5_OFF;
    f32x4 acc[4][8];
    #pragma unroll
    for (int j = 0; j < 8; ++j) {
      int c = wv + 4 * j;
      float bv = db5[c * 16 + l15];
      f32x4 bvv = {bv, bv, bv, bv};
      #pragma unroll
      for (int rf = 0; rf < 4; ++rf) acc[rf][j] = bvv;
    }
    bf16x8 az[4], as[4];
    #pragma unroll
    for (int rf = 0; rf < 4; ++rf) {
      az[rf] = *(const bf16x8*)&zs[rf * 16 + l15][hi8];
      as[rf] = *(const bf16x8*)&sA[(rf * 16 + l15) * 264 + hi8];
    }
    #pragma unroll
    for (int j = 0; j < 8; ++j) {
      int c = wv + 4 * j;
      bf16x8 bz = *(const bf16x8*)(W + (size_t)(c * 16 + l15) * 64 + hi8);
      bf16x8 bs = *(const bf16x8*)(W + (size_t)(c * 16 + l15) * 64 + 32 + hi8);
      #pragma unroll
      for (int rf = 0; rf < 4; ++rf) {
        acc[rf][j] = MFMA16(az[rf], bz, acc[rf][j]);
        acc[rf][j] = MFMA16(as[rf], bs, acc[rf][j]);
      }
    }
    #pragma unroll
    for (int j = 0; j < 8; ++j) {
      int c = wv + 4 * j;
      #pragma unroll
      for (int rf = 0; rf < 4; ++rf)
        #pragma unroll
        for (int r = 0; r < 4; ++r)
          zhout[(size_t)(m0 + rf * 16 + rloc + r) * 512 + c * 16 + l15] = (__bf16)acc[rf][j][r];
    }
  }
}

// =============================== decoder ===================================
// 16 independent MLPs 32 -> 64 -> 128 -> 256 (sigmoid after L0, L1), fp32 out.
__global__ __launch_bounds__(256, 2)
void dec_kernel(const __bf16* __restrict__ zin, const __bf16* __restrict__ wb,
                const float* __restrict__ b0, const float* __restrict__ b1,
                const float* __restrict__ b2, float* __restrict__ out)
{
  __shared__ __bf16 zs[64][40];
  __shared__ __bf16 h1[64][72];
  __shared__ __bf16 h2[64][136];
  const int e = blockIdx.y;
  const int m0 = blockIdx.x * 64;
  const int tid = threadIdx.x;
  const int lane = tid & 63, wv = tid >> 6;
  const int l15 = lane & 15, hi8 = (lane >> 4) * 8, rloc = (lane >> 4) * 4;

  {
    int r = tid >> 2, c = (tid & 3) * 8;
    *(bf16x8*)&zs[r][c] = *(const bf16x8*)(zin + (size_t)(m0 + r) * 512 + e * 32 + c);
  }
  __syncthreads();

  // L0: N=64, K=32
  {
    const __bf16* W = wb + DEC_W0_OFF + e * 2048;
    f32x4 acc[4];
    float bv = b0[e * 64 + wv * 16 + l15];
    f32x4 bvv = {bv, bv, bv, bv};
    #pragma unroll
    for (int rf = 0; rf < 4; ++rf) acc[rf] = bvv;
    bf16x8 a[4];
    #pragma unroll
    for (int rf = 0; rf < 4; ++rf) a[rf] = *(const bf16x8*)&zs[rf * 16 + l15][hi8];
    bf16x8 bb = *(const bf16x8*)(W + (size_t)(wv * 16 + l15) * 32 + hi8);
    #pragma unroll
    for (int rf = 0; rf < 4; ++rf) acc[rf] = MFMA16(a[rf], bb, acc[rf]);
    #pragma unroll
    for (int rf = 0; rf < 4; ++rf)
      #pragma unroll
      for (int r = 0; r < 4; ++r)
        h1[rf * 16 + rloc + r][wv * 16 + l15] = (__bf16)sigm(acc[rf][r]);
  }
  __syncthreads();

  // L1: N=128, K=64
  {
    const __bf16* W = wb + DEC_W1_OFF + e * 8192;
    f32x4 acc[4][2];
    #pragma unroll
    for (int cf = 0; cf < 2; ++cf) {
      float bv = b1[e * 128 + wv * 32 + cf * 16 + l15];
      f32x4 bvv = {bv, bv, bv, bv};
      #pragma unroll
      for (int rf = 0; rf < 4; ++rf) acc[rf][cf] = bvv;
    }
    #pragma unroll
    for (int ks = 0; ks < 2; ++ks) {
      bf16x8 a[4], bb[2];
      #pragma unroll
      for (int rf = 0; rf < 4; ++rf) a[rf] = *(const bf16x8*)&h1[rf * 16 + l15][ks * 32 + hi8];
      #pragma unroll
      for (int cf = 0; cf < 2; ++cf)
        bb[cf] = *(const bf16x8*)(W + (size_t)(wv * 32 + cf * 16 + l15) * 64 + ks * 32 + hi8);
      #pragma unroll
      for (int rf = 0; rf < 4; ++rf)
        #pragma unroll
        for (int cf = 0; cf < 2; ++cf)
          acc[rf][cf] = MFMA16(a[rf], bb[cf], acc[rf][cf]);
    }
    #pragma unroll
    for (int rf = 0; rf < 4; ++rf)
      #pragma unroll
      for (int cf = 0; cf < 2; ++cf)
        #pragma unroll
        for (int r = 0; r < 4; ++r)
          h2[rf * 16 + rloc + r][wv * 32 + cf * 16 + l15] = (__bf16)sigm(acc[rf][cf][r]);
  }
  __syncthreads();

  // L2: N=256, K=128, no sigmoid, fp32 out
  {
    const __bf16* W = wb + DEC_W2_OFF + e * 32768;
    f32x4 acc[4][4];
    #pragma unroll
    for (int cf = 0; cf < 4; ++cf) {
      float bv = b2[e * 256 + wv * 64 + cf * 16 + l15];
      f32x4 bvv = {bv, bv, bv, bv};
      #pragma unroll
      for (int rf = 0; rf < 4; ++rf) acc[rf][cf] = bvv;
    }
    #pragma unroll
    for (int ks = 0; ks < 4; ++ks) {
      bf16x8 a[4], bb[4];
      #pragma unroll
      for (int rf = 0; rf < 4; ++rf) a[rf] = *(const bf16x8*)&h2[rf * 16 + l15][ks * 32 + hi8];
      #pragma unroll
      for (int cf = 0; cf < 4; ++cf)
        bb[cf] = *(const bf16x8*)(W + (size_t)(wv * 64 + cf * 16 + l15) * 128 + ks * 32 + hi8);
      #pragma unroll
      for (int rf = 0; rf < 4; ++rf)
        #pragma unroll
        for (int cf = 0; cf < 4; ++cf)
          acc[rf][cf] = MFMA16(a[rf], bb[cf], acc[rf][cf]);
    }
    #pragma unroll
    for (int rf = 0; rf < 4; ++rf)
      #pragma unroll
      for (int cf = 0; cf < 4; ++cf)
        #pragma unroll
        for (int r = 0; r < 4; ++r)
          out[(size_t)(m0 + rf * 16 + rloc + r) * 4096 + e * 256 + wv * 64 + cf * 16 + l15] =
              acc[rf][cf][r];
  }
}

// =============================== launcher ==================================
extern "C" void kernel_launch(void* const* d_in, const int* in_sizes, int n_in,
                              void* d_out, int out_size, void* d_ws, size_t ws_size,
                              hipStream_t stream) {
  (void)in_sizes; (void)n_in; (void)out_size; (void)ws_size;
  const float* x   = (const float*)d_in[0];
  const float* ew0 = (const float*)d_in[1];  const float* eb0 = (const float*)d_in[2];
  const float* ew1 = (const float*)d_in[3];  const float* eb1 = (const float*)d_in[4];
  const float* ew2 = (const float*)d_in[5];  const float* eb2 = (const float*)d_in[6];
  const float* dw0 = (const float*)d_in[7];  const float* db0 = (const float*)d_in[8];
  const float* dw1 = (const float*)d_in[9];  const float* db1 = (const float*)d_in[10];
  const float* dw2 = (const float*)d_in[11]; const float* db2 = (const float*)d_in[12];
  const float* cw[6]; const float* cb[6];
  for (int i = 0; i < 6; ++i) { cw[i] = (const float*)d_in[13 + 2 * i]; cb[i] = (const float*)d_in[14 + 2 * i]; }
  const float* xw[6]; const float* xb[6];
  for (int i = 0; i < 6; ++i) { xw[i] = (const float*)d_in[25 + 2 * i]; xb[i] = (const float*)d_in[26 + 2 * i]; }

  __bf16* wbuf   = (__bf16*)d_ws;
  __bf16* zstack = (__bf16*)((char*)d_ws + ZS_BYTES_OFF);  // also reused for z_stack_hat
  __bf16* zbuf   = (__bf16*)((char*)d_ws + Z_BYTES_OFF);
  float* out = (float*)d_out;

  prep_kernel<<<1024, 256, 0, stream>>>(ew0, ew1, ew2, dw0, dw1, dw2,
                                        cw[0], cw[1], cw[2], cw[3], cw[4], cw[5],
                                        xw[0], xw[1], xw[2], xw[3], xw[4], xw[5], wbuf);
  enc_kernel<<<dim3(512, 16), 256, 0, stream>>>(x, wbuf, eb0, eb1, eb2, zstack);
  comp_kernel<<<512, 256, 0, stream>>>(zstack, wbuf, cb[0], cb[1], cb[2], cb[3], cb[4], cb[5], zbuf);
  decomp_kernel<<<512, 256, 0, stream>>>(zbuf, wbuf, xb[0], xb[1], xb[2], xb[3], xb[4], xb[5], zstack);
  dec_kernel<<<dim3(512, 16), 256, 0, stream>>>(zstack, wbuf, db0, db1, db2, out);
}